// Round 20
// baseline (34.502 us; speedup 1.0000x reference)
//
#include <hip/hip_runtime.h>

// ---------------------------------------------------------------------------
// QuantumEntanglementLayer: 4 qubits, DIM=16, BATCH=2^20.
// out[b][w] = s^T A_w s,  A_w = Re(U^H Z_w U),  s = tensor prod of RY(|0>).
// Reduced to 4 multilinear polynomials with 81 coeffs each in (1,u_w,v_w),
// u_w = cos(tanh(x_w)*pi/2), v_w = sin(tanh(x_w)*pi/2).
//
// MEASUREMENT ROUND: byte-identical to the 19.57us r18 kernel (session
// best: shuffle setup + 8-sample rolled scalar contract), dispatched TWICE
// (idempotent). K18 = total - 19.57 isolates the kernel's own duration;
// F = 19.57 - K18 is the fixed launch/harness floor. r19's forced-pk
// regression (+1.6us) plus r17's scalarized null proved contract-issue is
// not binding; this probe decides "continue vs declare" with data.
// ---------------------------------------------------------------------------

__device__ __forceinline__ float hwsin(float rad) {
  return __builtin_amdgcn_sinf(rad * 0.15915494309189535f);  // rad -> rev
}
__device__ __forceinline__ float hwcos(float rad) {
  return __builtin_amdgcn_cosf(rad * 0.15915494309189535f);
}

#define TRIGM(xv, U, V) { \
  float e_  = __builtin_amdgcn_exp2f((xv) * 2.8853900817779268f); \
  float th_ = 1.0f - 2.0f * __builtin_amdgcn_rcpf(e_ + 1.0f); \
  U = __builtin_amdgcn_cosf(th_ * 0.25f); \
  V = __builtin_amdgcn_sinf(th_ * 0.25f); }

#define SAMPLE_TRIG(K, XK) \
  TRIGM(XK.x, u0_##K, v0_##K) TRIGM(XK.y, u1_##K, v1_##K) \
  TRIGM(XK.z, u2_##K, v2_##K) TRIGM(XK.w, u3_##K, v3_##K)

#define DECL_TRIG(K) \
  float u0_##K, v0_##K, u1_##K, v1_##K, u2_##K, v2_##K, u3_##K, v3_##K;

#define ACC3(K) { \
  float t_ = fmaf(c.z, v3_##K, fmaf(c.y, u3_##K, c.x)); \
  if (e3 == 0) a3_##K = t_; \
  else a3_##K = fmaf(t_, (e3 == 1) ? u2_##K : v2_##K, a3_##K); }

#define ACC2(K) { \
  if (e2 == 0) a2_##K = a3_##K; \
  else a2_##K = fmaf(a3_##K, (e2 == 1) ? u1_##K : v1_##K, a2_##K); }

// e1 is a RUNTIME loop index: select via cndmask, guard via select.
#define ACC1R(K) { \
  float m_ = (e1 == 1) ? u0_##K : v0_##K; \
  a1_##K = (e1 == 0) ? a2_##K : fmaf(a2_##K, m_, a1_##K); }

#define ALL8(M) M(0) M(1) M(2) M(3) M(4) M(5) M(6) M(7)

__global__ __launch_bounds__(256) void qel_fused(const float4* __restrict__ x4,
                                                 const float* __restrict__ params,
                                                 float4* __restrict__ out4,
                                                 int eighth) {
  __shared__ float2 U2[16][17];            // final U [col][row], +1 pad
  __shared__ float A[4][16][16];           // A_w
  __shared__ float S1[4][3][8][8];         // after contracting qubit0 (f0)
  __shared__ float S2[4][3][3][4][4];      // + qubit1 (f1)
  __shared__ float S3[4][3][3][3][2][2];   // + qubit2 (f2)
  __shared__ float4 Cs[108];               // final coefficients
  __shared__ float Olds[4][8][256];        // [wire][sample][tid] out slots

  const int tid = threadIdx.x;
  const int gid = blockIdx.x * 256 + tid;
  const bool act = gid < eighth;
  const int g = act ? gid : 0;

  // Sample loads first: HBM latency hides under the circuit phases.
  float4 X0 = x4[g];
  float4 X1 = x4[g + eighth];
  float4 X2 = x4[g + 2 * eighth];
  float4 X3 = x4[g + 3 * eighth];
  float4 X4 = x4[g + 4 * eighth];
  float4 X5 = x4[g + 5 * eighth];
  float4 X6 = x4[g + 6 * eighth];
  float4 X7 = x4[g + 7 * eighth];

  // ---- Setup phase 1 (shuffle-parallel, barrier-free) --------------------
  {
    const int c = tid >> 4, r = tid & 15;
    float vr = (r == c) ? 1.f : 0.f;
    float vi = 0.f;

    #pragma unroll
    for (int layer = 0; layer < 2; layer++) {
      #pragma unroll
      for (int i = 0; i < 3; i++) {        // CNOT(i,i+1): cm=8>>i, tm=4>>i
        const int cm = 8 >> i, tm = 4 >> i;
        float pvr = __shfl_xor(vr, tm);
        float pvi = __shfl_xor(vi, tm);
        vr = (r & cm) ? pvr : vr;
        vi = (r & cm) ? pvi : vi;
      }
      #pragma unroll
      for (int w = 0; w < 4; w++) {        // Rot(phi,theta,omega) on wire w
        float phi   = params[layer * 12 + w * 3 + 0];
        float theta = params[layer * 12 + w * 3 + 1];
        float omega = params[layer * 12 + w * 3 + 2];
        float ct = hwcos(theta * 0.5f), st = hwsin(theta * 0.5f);
        float ap = -0.5f * (phi + omega), am = 0.5f * (phi - omega);
        float g00r =  hwcos(ap) * ct, g00i =  hwsin(ap) * ct;
        float g01r = -hwcos(am) * st, g01i = -hwsin(am) * st;
        float g10r =  hwcos(am) * st, g10i = -hwsin(am) * st;
        float g11r =  g00r,           g11i = -g00i;
        const int tm = 8 >> w;
        const bool hi = (r & tm) != 0;
        float pvr = __shfl_xor(vr, tm);
        float pvi = __shfl_xor(vi, tm);
        float o0r = hi ? pvr : vr, o0i = hi ? pvi : vi;
        float o1r = hi ? vr : pvr, o1i = hi ? vi : pvi;
        float gar = hi ? g10r : g00r, gai = hi ? g10i : g00i;
        float gbr = hi ? g11r : g01r, gbi = hi ? g11i : g01i;
        vr = gar * o0r - gai * o0i + gbr * o1r - gbi * o1i;
        vi = gar * o0i + gai * o0r + gbr * o1i + gbi * o1r;
      }
      {                                    // CNOT(0,3): cm=8, tm=1
        float pvr = __shfl_xor(vr, 1);
        float pvi = __shfl_xor(vi, 1);
        vr = (r & 8) ? pvr : vr;
        vi = (r & 8) ? pvi : vi;
      }
    }
    U2[c][r] = make_float2(vr, vi);
  }
  __syncthreads();

  // ---- Setup phase 2: A_w[j][k] = sum_i z_w[i] Re(conj(U_ij) U_ik) -------
  {
    const int j = tid >> 4, k = tid & 15;
    float s0 = 0.f, s1 = 0.f, s2 = 0.f, s3 = 0.f;
    #pragma unroll
    for (int i = 0; i < 16; i++) {
      float2 uj = U2[j][i], uk = U2[k][i];
      float p = uj.x * uk.x + uj.y * uk.y;
      s0 += (i & 8) ? -p : p;
      s1 += (i & 4) ? -p : p;
      s2 += (i & 2) ? -p : p;
      s3 += (i & 1) ? -p : p;
    }
    A[0][j][k] = s0; A[1][j][k] = s1; A[2][j][k] = s2; A[3][j][k] = s3;
  }
  __syncthreads();

  // Basis per 2x2 block: f=0: .5(x00+x11)  f=1: .5(x00-x11)  f=2: .5(x01+x10)
  {  // Phase 3a: contract qubit0 (bit3)
    const int w = tid >> 6, j = (tid >> 3) & 7, k = tid & 7;
    float x00 = A[w][j][k],     x01 = A[w][j][k + 8];
    float x10 = A[w][j + 8][k], x11 = A[w][j + 8][k + 8];
    S1[w][0][j][k] = 0.5f * (x00 + x11);
    S1[w][1][j][k] = 0.5f * (x00 - x11);
    S1[w][2][j][k] = 0.5f * (x01 + x10);
  }
  __syncthreads();
  if (tid < 192) {  // Phase 3b: + qubit1
    const int w = tid / 48, r = tid % 48;
    const int f0 = r >> 4, j = (r >> 2) & 3, k = r & 3;
    float x00 = S1[w][f0][j][k],     x01 = S1[w][f0][j][k + 4];
    float x10 = S1[w][f0][j + 4][k], x11 = S1[w][f0][j + 4][k + 4];
    S2[w][f0][0][j][k] = 0.5f * (x00 + x11);
    S2[w][f0][1][j][k] = 0.5f * (x00 - x11);
    S2[w][f0][2][j][k] = 0.5f * (x01 + x10);
  }
  __syncthreads();
  if (tid < 144) {  // Phase 3c: + qubit2
    const int w = tid / 36, r = tid % 36;
    const int f0 = r / 12, f1 = (r >> 2) % 3, j = (r >> 1) & 1, k = r & 1;
    float x00 = S2[w][f0][f1][j][k],     x01 = S2[w][f0][f1][j][k + 2];
    float x10 = S2[w][f0][f1][j + 2][k], x11 = S2[w][f0][f1][j + 2][k + 2];
    S3[w][f0][f1][0][j][k] = 0.5f * (x00 + x11);
    S3[w][f0][f1][1][j][k] = 0.5f * (x00 - x11);
    S3[w][f0][f1][2][j][k] = 0.5f * (x01 + x10);
  }
  __syncthreads();
  if (tid < 108) {  // Phase 3d: + qubit3 -> float4 per (w,f0,f1,f2)
    const int w = tid / 27, r = tid % 27;
    const int f0 = r / 9, f1 = (r / 3) % 3, f2 = r % 3;
    float y00 = S3[w][f0][f1][f2][0][0], y01 = S3[w][f0][f1][f2][0][1];
    float y10 = S3[w][f0][f1][f2][1][0], y11 = S3[w][f0][f1][f2][1][1];
    float4 o;
    o.x = 0.5f * (y00 + y11);
    o.y = 0.5f * (y00 - y11);
    o.z = 0.5f * (y01 + y10);
    o.w = 0.f;
    Cs[tid] = o;
  }

  // ---- Per-sample trig ----------------------------------------------------
  ALL8(DECL_TRIG)
  SAMPLE_TRIG(0, X0) SAMPLE_TRIG(1, X1) SAMPLE_TRIG(2, X2) SAMPLE_TRIG(3, X3)
  SAMPLE_TRIG(4, X4) SAMPLE_TRIG(5, X5) SAMPLE_TRIG(6, X6) SAMPLE_TRIG(7, X7)

  __syncthreads();

  // ---- Rolled polynomial contraction (8 samples/thread) ------------------
  #pragma unroll 1
  for (int W = 0; W < 4; W++) {
    float a1_0 = 0.f, a1_1 = 0.f, a1_2 = 0.f, a1_3 = 0.f;
    float a1_4 = 0.f, a1_5 = 0.f, a1_6 = 0.f, a1_7 = 0.f;
    #pragma unroll 1
    for (int e1 = 0; e1 < 3; e1++) {
      const float4* cb = &Cs[W * 27 + e1 * 9];   // runtime base, imm offsets
      float a2_0, a2_1, a2_2, a2_3, a2_4, a2_5, a2_6, a2_7;
      #pragma unroll
      for (int e2 = 0; e2 < 3; e2++) {
        float a3_0, a3_1, a3_2, a3_3, a3_4, a3_5, a3_6, a3_7;
        #pragma unroll
        for (int e3 = 0; e3 < 3; e3++) {
          float4 c = cb[e2 * 3 + e3];
          ALL8(ACC3)
        }
        ALL8(ACC2)
      }
      ALL8(ACC1R)
    }
    Olds[W][0][tid] = a1_0;
    Olds[W][1][tid] = a1_1;
    Olds[W][2][tid] = a1_2;
    Olds[W][3][tid] = a1_3;
    Olds[W][4][tid] = a1_4;
    Olds[W][5][tid] = a1_5;
    Olds[W][6][tid] = a1_6;
    Olds[W][7][tid] = a1_7;
  }

  // Same-thread LDS slots: no barrier needed (compiler inserts lgkmcnt).
  if (act) {
    #pragma unroll
    for (int k = 0; k < 8; k++) {
      out4[gid + k * eighth] = make_float4(Olds[0][k][tid], Olds[1][k][tid],
                                           Olds[2][k][tid], Olds[3][k][tid]);
    }
  }
}

// ---------------------------------------------------------------------------

extern "C" void kernel_launch(void* const* d_in, const int* in_sizes, int n_in,
                              void* d_out, int out_size, void* d_ws, size_t ws_size,
                              hipStream_t stream) {
  const float* x      = (const float*)d_in[0];   // [B,4] f32
  const float* params = (const float*)d_in[1];   // [2,4,3] f32
  float* out = (float*)d_out;                    // [B,4] f32

  int B = in_sizes[0] / 4;
  int eighth = B / 8;
  int blocks = (eighth + 255) / 256;

  // Dispatched TWICE on purpose (idempotent): K18 = total - 19.57us,
  // F = 19.57 - K18. Decides "continue optimizing vs declare roofline".
  qel_fused<<<blocks, 256, 0, stream>>>((const float4*)x, params,
                                        (float4*)out, eighth);
  qel_fused<<<blocks, 256, 0, stream>>>((const float4*)x, params,
                                        (float4*)out, eighth);
}

// Round 21
// 19.815 us; speedup vs baseline: 1.7412x; 1.7412x over previous
//
#include <hip/hip_runtime.h>

// ---------------------------------------------------------------------------
// QuantumEntanglementLayer: 4 qubits, DIM=16, BATCH=2^20.
// out[b][w] = s^T A_w s,  A_w = Re(U^H Z_w U),  s = tensor prod of RY(|0>).
// Reduced to 4 multilinear polynomials with 81 coeffs each in (1,u_w,v_w),
// u_w = cos(tanh(x_w)*pi/2), v_w = sin(tanh(x_w)*pi/2).
//
// FINAL FORM (session: 39.0 -> 19.57us, 2.0x). Structure:
//   - single fused dispatch (two-kernel split pays ~2x launch floor)
//   - per-block setup: barrier-free __shfl_xor circuit (U columns evolve
//     within 16-lane groups), LDS-parallel A_w + basis contraction
//   - 8 samples/thread (512 blocks), scalar trig via exp2/rcp/sin/cos
//   - ROLLED W/e1 contract loops: the unrolled 14KB body ballooned the
//     allocator to 240-256 VGPR (2 waves/SIMD latency-bound); rolling
//     bounds the Cs-load hoist window structurally. All occupancy
//     attributes measured poison (64-VGPR spill storm). Runtime-W outputs
//     via same-thread LDS slots (rule-#20-safe), gathered to float4.
// Measured decomposition (r20 double-dispatch probe): kernel 14.9us,
// fixed launch/harness floor ~4.6us, HBM floor ~5.3us of the 14.9.
// Issue-halving (pk-math) measured null-to-negative; LDS-traffic halving
// measured -0.9us; remaining ~5us is latency structure at 2 waves/SIMD.
// ---------------------------------------------------------------------------

__device__ __forceinline__ float hwsin(float rad) {
  return __builtin_amdgcn_sinf(rad * 0.15915494309189535f);  // rad -> rev
}
__device__ __forceinline__ float hwcos(float rad) {
  return __builtin_amdgcn_cosf(rad * 0.15915494309189535f);
}

#define TRIGM(xv, U, V) { \
  float e_  = __builtin_amdgcn_exp2f((xv) * 2.8853900817779268f); \
  float th_ = 1.0f - 2.0f * __builtin_amdgcn_rcpf(e_ + 1.0f); \
  U = __builtin_amdgcn_cosf(th_ * 0.25f); \
  V = __builtin_amdgcn_sinf(th_ * 0.25f); }

#define SAMPLE_TRIG(K, XK) \
  TRIGM(XK.x, u0_##K, v0_##K) TRIGM(XK.y, u1_##K, v1_##K) \
  TRIGM(XK.z, u2_##K, v2_##K) TRIGM(XK.w, u3_##K, v3_##K)

#define DECL_TRIG(K) \
  float u0_##K, v0_##K, u1_##K, v1_##K, u2_##K, v2_##K, u3_##K, v3_##K;

#define ACC3(K) { \
  float t_ = fmaf(c.z, v3_##K, fmaf(c.y, u3_##K, c.x)); \
  if (e3 == 0) a3_##K = t_; \
  else a3_##K = fmaf(t_, (e3 == 1) ? u2_##K : v2_##K, a3_##K); }

#define ACC2(K) { \
  if (e2 == 0) a2_##K = a3_##K; \
  else a2_##K = fmaf(a3_##K, (e2 == 1) ? u1_##K : v1_##K, a2_##K); }

// e1 is a RUNTIME loop index: select via cndmask, guard via select.
#define ACC1R(K) { \
  float m_ = (e1 == 1) ? u0_##K : v0_##K; \
  a1_##K = (e1 == 0) ? a2_##K : fmaf(a2_##K, m_, a1_##K); }

#define ALL8(M) M(0) M(1) M(2) M(3) M(4) M(5) M(6) M(7)

__global__ __launch_bounds__(256) void qel_fused(const float4* __restrict__ x4,
                                                 const float* __restrict__ params,
                                                 float4* __restrict__ out4,
                                                 int eighth) {
  __shared__ float2 U2[16][17];            // final U [col][row], +1 pad
  __shared__ float A[4][16][16];           // A_w
  __shared__ float S1[4][3][8][8];         // after contracting qubit0 (f0)
  __shared__ float S2[4][3][3][4][4];      // + qubit1 (f1)
  __shared__ float S3[4][3][3][3][2][2];   // + qubit2 (f2)
  __shared__ float4 Cs[108];               // final coefficients
  __shared__ float Olds[4][8][256];        // [wire][sample][tid] out slots

  const int tid = threadIdx.x;
  const int gid = blockIdx.x * 256 + tid;
  const bool act = gid < eighth;
  const int g = act ? gid : 0;

  // Sample loads first: HBM latency hides under the circuit phases.
  float4 X0 = x4[g];
  float4 X1 = x4[g + eighth];
  float4 X2 = x4[g + 2 * eighth];
  float4 X3 = x4[g + 3 * eighth];
  float4 X4 = x4[g + 4 * eighth];
  float4 X5 = x4[g + 5 * eighth];
  float4 X6 = x4[g + 6 * eighth];
  float4 X7 = x4[g + 7 * eighth];

  // ---- Setup phase 1 (shuffle-parallel, barrier-free) --------------------
  {
    const int c = tid >> 4, r = tid & 15;
    float vr = (r == c) ? 1.f : 0.f;
    float vi = 0.f;

    #pragma unroll
    for (int layer = 0; layer < 2; layer++) {
      #pragma unroll
      for (int i = 0; i < 3; i++) {        // CNOT(i,i+1): cm=8>>i, tm=4>>i
        const int cm = 8 >> i, tm = 4 >> i;
        float pvr = __shfl_xor(vr, tm);
        float pvi = __shfl_xor(vi, tm);
        vr = (r & cm) ? pvr : vr;
        vi = (r & cm) ? pvi : vi;
      }
      #pragma unroll
      for (int w = 0; w < 4; w++) {        // Rot(phi,theta,omega) on wire w
        float phi   = params[layer * 12 + w * 3 + 0];
        float theta = params[layer * 12 + w * 3 + 1];
        float omega = params[layer * 12 + w * 3 + 2];
        float ct = hwcos(theta * 0.5f), st = hwsin(theta * 0.5f);
        float ap = -0.5f * (phi + omega), am = 0.5f * (phi - omega);
        float g00r =  hwcos(ap) * ct, g00i =  hwsin(ap) * ct;
        float g01r = -hwcos(am) * st, g01i = -hwsin(am) * st;
        float g10r =  hwcos(am) * st, g10i = -hwsin(am) * st;
        float g11r =  g00r,           g11i = -g00i;
        const int tm = 8 >> w;
        const bool hi = (r & tm) != 0;
        float pvr = __shfl_xor(vr, tm);
        float pvi = __shfl_xor(vi, tm);
        float o0r = hi ? pvr : vr, o0i = hi ? pvi : vi;
        float o1r = hi ? vr : pvr, o1i = hi ? vi : pvi;
        float gar = hi ? g10r : g00r, gai = hi ? g10i : g00i;
        float gbr = hi ? g11r : g01r, gbi = hi ? g11i : g01i;
        vr = gar * o0r - gai * o0i + gbr * o1r - gbi * o1i;
        vi = gar * o0i + gai * o0r + gbr * o1i + gbi * o1r;
      }
      {                                    // CNOT(0,3): cm=8, tm=1
        float pvr = __shfl_xor(vr, 1);
        float pvi = __shfl_xor(vi, 1);
        vr = (r & 8) ? pvr : vr;
        vi = (r & 8) ? pvi : vi;
      }
    }
    U2[c][r] = make_float2(vr, vi);
  }
  __syncthreads();

  // ---- Setup phase 2: A_w[j][k] = sum_i z_w[i] Re(conj(U_ij) U_ik) -------
  {
    const int j = tid >> 4, k = tid & 15;
    float s0 = 0.f, s1 = 0.f, s2 = 0.f, s3 = 0.f;
    #pragma unroll
    for (int i = 0; i < 16; i++) {
      float2 uj = U2[j][i], uk = U2[k][i];
      float p = uj.x * uk.x + uj.y * uk.y;
      s0 += (i & 8) ? -p : p;
      s1 += (i & 4) ? -p : p;
      s2 += (i & 2) ? -p : p;
      s3 += (i & 1) ? -p : p;
    }
    A[0][j][k] = s0; A[1][j][k] = s1; A[2][j][k] = s2; A[3][j][k] = s3;
  }
  __syncthreads();

  // Basis per 2x2 block: f=0: .5(x00+x11)  f=1: .5(x00-x11)  f=2: .5(x01+x10)
  {  // Phase 3a: contract qubit0 (bit3)
    const int w = tid >> 6, j = (tid >> 3) & 7, k = tid & 7;
    float x00 = A[w][j][k],     x01 = A[w][j][k + 8];
    float x10 = A[w][j + 8][k], x11 = A[w][j + 8][k + 8];
    S1[w][0][j][k] = 0.5f * (x00 + x11);
    S1[w][1][j][k] = 0.5f * (x00 - x11);
    S1[w][2][j][k] = 0.5f * (x01 + x10);
  }
  __syncthreads();
  if (tid < 192) {  // Phase 3b: + qubit1
    const int w = tid / 48, r = tid % 48;
    const int f0 = r >> 4, j = (r >> 2) & 3, k = r & 3;
    float x00 = S1[w][f0][j][k],     x01 = S1[w][f0][j][k + 4];
    float x10 = S1[w][f0][j + 4][k], x11 = S1[w][f0][j + 4][k + 4];
    S2[w][f0][0][j][k] = 0.5f * (x00 + x11);
    S2[w][f0][1][j][k] = 0.5f * (x00 - x11);
    S2[w][f0][2][j][k] = 0.5f * (x01 + x10);
  }
  __syncthreads();
  if (tid < 144) {  // Phase 3c: + qubit2
    const int w = tid / 36, r = tid % 36;
    const int f0 = r / 12, f1 = (r >> 2) % 3, j = (r >> 1) & 1, k = r & 1;
    float x00 = S2[w][f0][f1][j][k],     x01 = S2[w][f0][f1][j][k + 2];
    float x10 = S2[w][f0][f1][j + 2][k], x11 = S2[w][f0][f1][j + 2][k + 2];
    S3[w][f0][f1][0][j][k] = 0.5f * (x00 + x11);
    S3[w][f0][f1][1][j][k] = 0.5f * (x00 - x11);
    S3[w][f0][f1][2][j][k] = 0.5f * (x01 + x10);
  }
  __syncthreads();
  if (tid < 108) {  // Phase 3d: + qubit3 -> float4 per (w,f0,f1,f2)
    const int w = tid / 27, r = tid % 27;
    const int f0 = r / 9, f1 = (r / 3) % 3, f2 = r % 3;
    float y00 = S3[w][f0][f1][f2][0][0], y01 = S3[w][f0][f1][f2][0][1];
    float y10 = S3[w][f0][f1][f2][1][0], y11 = S3[w][f0][f1][f2][1][1];
    float4 o;
    o.x = 0.5f * (y00 + y11);
    o.y = 0.5f * (y00 - y11);
    o.z = 0.5f * (y01 + y10);
    o.w = 0.f;
    Cs[tid] = o;
  }

  // ---- Per-sample trig ----------------------------------------------------
  ALL8(DECL_TRIG)
  SAMPLE_TRIG(0, X0) SAMPLE_TRIG(1, X1) SAMPLE_TRIG(2, X2) SAMPLE_TRIG(3, X3)
  SAMPLE_TRIG(4, X4) SAMPLE_TRIG(5, X5) SAMPLE_TRIG(6, X6) SAMPLE_TRIG(7, X7)

  __syncthreads();

  // ---- Rolled polynomial contraction (8 samples/thread) ------------------
  #pragma unroll 1
  for (int W = 0; W < 4; W++) {
    float a1_0 = 0.f, a1_1 = 0.f, a1_2 = 0.f, a1_3 = 0.f;
    float a1_4 = 0.f, a1_5 = 0.f, a1_6 = 0.f, a1_7 = 0.f;
    #pragma unroll 1
    for (int e1 = 0; e1 < 3; e1++) {
      const float4* cb = &Cs[W * 27 + e1 * 9];   // runtime base, imm offsets
      float a2_0, a2_1, a2_2, a2_3, a2_4, a2_5, a2_6, a2_7;
      #pragma unroll
      for (int e2 = 0; e2 < 3; e2++) {
        float a3_0, a3_1, a3_2, a3_3, a3_4, a3_5, a3_6, a3_7;
        #pragma unroll
        for (int e3 = 0; e3 < 3; e3++) {
          float4 c = cb[e2 * 3 + e3];
          ALL8(ACC3)
        }
        ALL8(ACC2)
      }
      ALL8(ACC1R)
    }
    Olds[W][0][tid] = a1_0;
    Olds[W][1][tid] = a1_1;
    Olds[W][2][tid] = a1_2;
    Olds[W][3][tid] = a1_3;
    Olds[W][4][tid] = a1_4;
    Olds[W][5][tid] = a1_5;
    Olds[W][6][tid] = a1_6;
    Olds[W][7][tid] = a1_7;
  }

  // Same-thread LDS slots: no barrier needed (compiler inserts lgkmcnt).
  if (act) {
    #pragma unroll
    for (int k = 0; k < 8; k++) {
      out4[gid + k * eighth] = make_float4(Olds[0][k][tid], Olds[1][k][tid],
                                           Olds[2][k][tid], Olds[3][k][tid]);
    }
  }
}

// ---------------------------------------------------------------------------

extern "C" void kernel_launch(void* const* d_in, const int* in_sizes, int n_in,
                              void* d_out, int out_size, void* d_ws, size_t ws_size,
                              hipStream_t stream) {
  const float* x      = (const float*)d_in[0];   // [B,4] f32
  const float* params = (const float*)d_in[1];   // [2,4,3] f32
  float* out = (float*)d_out;                    // [B,4] f32

  int B = in_sizes[0] / 4;
  int eighth = B / 8;
  int blocks = (eighth + 255) / 256;

  qel_fused<<<blocks, 256, 0, stream>>>((const float4*)x, params,
                                        (float4*)out, eighth);
}